// Round 1
// baseline (36.712 us; speedup 1.0000x reference)
//
#include <hip/hip_runtime.h>

// Signature kernel via Goursat PDE, dyadic_order=1.
// xs: (32,64,16) f32, ys: (32,64,16) f32 -> out: (32,32) f32.
//
// Key identity: inc[l,m] = <xs[a,l+1]-xs[a,l], ys[b,m+1]-ys[b,m]> / 4,
// vf[i,j] = inc[i>>1, j>>1]  (126x126 grid). PDE:
//   K[r][c] = c1*(K[r][c-1]+K[r-1][c]) - c2*K[r-1][c-1],  K[0][*]=K[*][0]=1
//   c1 = 1 + v/2 + v^2/12,  c2 = 1 - v^2/12,  v = vf[r-1][c-1]
// Output = K[126][126] per (a,b) pair.
//
// Parallelization: anti-diagonal wavefront, one wave (64 threads) per pair.
// Thread p owns K-columns jA=2p+1, jB=2p+2 (both use dy[p]).
// Cell (r,c) computed at step t=r+c; neighbor column values flow via
// __shfl_up (no __syncthreads in the scan).

#define NL 64   // path length
#define ND 16   // feature dim
#define NQ 63   // number of increments
#define MM 126  // refined PDE grid size (2*NQ)
#define STR 20  // padded LDS row stride in floats (20 mod 32 -> conflict-free b128)

__global__ void __launch_bounds__(64)
sig_pde_kernel(const float* __restrict__ xs,
               const float* __restrict__ ys,
               float* __restrict__ out)
{
    __shared__ float sdx[NQ * STR];

    const int a = blockIdx.y;
    const int b = blockIdx.x;
    const int p = threadIdx.x;

    const float* xa = xs + a * (NL * ND);
    const float* yb = ys + b * (NL * ND);

    // dy[p] (= ys increments, column-half owned by this thread) in registers
    float4 dy0, dy1, dy2, dy3;
    dy0 = dy1 = dy2 = dy3 = make_float4(0.f, 0.f, 0.f, 0.f);

    if (p < NQ) {
        // dx row p -> LDS (xs increments, shared across threads)
        const float4* x0 = reinterpret_cast<const float4*>(xa + p * ND);
        const float4* x1 = reinterpret_cast<const float4*>(xa + (p + 1) * ND);
        float* dst = &sdx[p * STR];
#pragma unroll
        for (int e = 0; e < 4; ++e) {
            float4 u = x1[e];
            float4 v = x0[e];
            float4 w = make_float4(u.x - v.x, u.y - v.y, u.z - v.z, u.w - v.w);
            *reinterpret_cast<float4*>(dst + e * 4) = w;
        }
        const float4* y0 = reinterpret_cast<const float4*>(yb + p * ND);
        const float4* y1 = reinterpret_cast<const float4*>(yb + (p + 1) * ND);
        float4 s, t;
        s = y0[0]; t = y1[0]; dy0 = make_float4(t.x - s.x, t.y - s.y, t.z - s.z, t.w - s.w);
        s = y0[1]; t = y1[1]; dy1 = make_float4(t.x - s.x, t.y - s.y, t.z - s.z, t.w - s.w);
        s = y0[2]; t = y1[2]; dy2 = make_float4(t.x - s.x, t.y - s.y, t.z - s.z, t.w - s.w);
        s = y0[3]; t = y1[3]; dy3 = make_float4(t.x - s.x, t.y - s.y, t.z - s.z, t.w - s.w);
    }
    __syncthreads();

    // Column state. kA1/kA2: column jA at (t-1, t-2); same for kB.
    float kA1 = 1.f, kA2 = 1.f, kB1 = 1.f, kB2 = 1.f;
    // c1A/c2A: coefficients for column-pair at current A-row; B trails by one row.
    float c1A = 1.f, c2A = 1.f, c1B = 1.f, c2B = 1.f;

    const bool colOK = (p < NQ);
    const int twop1 = 2 * p + 1;

    for (int tt = 0; tt < 126; ++tt) {
        // ---------- even step: t = 2 + 2*tt  (rA odd -> new q, new dot) ----------
        {
            const int t  = 2 + 2 * tt;
            const int rA = t - twop1;          // row of column jA this step
            float nb1 = __shfl_up(kB1, 1, 64); // neighbor K[rA  ][2p]
            float nb2 = __shfl_up(kB2, 1, 64); // neighbor K[rA-1][2p]
            if (p == 0) { nb1 = 1.f; nb2 = 1.f; }
            const bool actA = colOK && (rA >= 1) && (rA <= MM);
            const bool actB = colOK && (rA >= 2) && (rA <= MM + 1);

            if (actA) {
                const int q = (rA - 1) >> 1;
                const float* dxr = &sdx[q * STR];
                float4 a0 = *reinterpret_cast<const float4*>(dxr);
                float4 a1 = *reinterpret_cast<const float4*>(dxr + 4);
                float4 a2 = *reinterpret_cast<const float4*>(dxr + 8);
                float4 a3 = *reinterpret_cast<const float4*>(dxr + 12);
                float dot = a0.x * dy0.x + a0.y * dy0.y + a0.z * dy0.z + a0.w * dy0.w
                          + a1.x * dy1.x + a1.y * dy1.y + a1.z * dy1.z + a1.w * dy1.w
                          + a2.x * dy2.x + a2.y * dy2.y + a2.z * dy2.z + a2.w * dy2.w
                          + a3.x * dy3.x + a3.y * dy3.y + a3.z * dy3.z + a3.w * dy3.w;
                const float v  = 0.25f * dot;
                const float v2 = v * v * (1.0f / 12.0f);
                c1A = 1.f + 0.5f * v + v2;
                c2A = 1.f - v2;
            }
            // B first: uses pre-update kA1 (left=K[rB][jA]) and kA2 (diag=K[rB-1][jA])
            if (actB) {
                const float kn = c1B * (kA1 + kB1) - c2B * kA2;
                kB2 = kB1; kB1 = kn;
            }
            if (actA) {
                const float kn = c1A * (nb1 + kA1) - c2A * nb2;
                kA2 = kA1; kA1 = kn;
            }
            c1B = c1A; c2B = c2A;  // B trails A by one row
        }
        // ---------- odd step: t = 3 + 2*tt  (rA even -> same q, keep dot) ----------
        {
            const int t  = 3 + 2 * tt;
            const int rA = t - twop1;
            float nb1 = __shfl_up(kB1, 1, 64);
            float nb2 = __shfl_up(kB2, 1, 64);
            if (p == 0) { nb1 = 1.f; nb2 = 1.f; }
            const bool actA = colOK && (rA >= 1) && (rA <= MM);
            const bool actB = colOK && (rA >= 2) && (rA <= MM + 1);

            if (actB) {
                const float kn = c1B * (kA1 + kB1) - c2B * kA2;
                kB2 = kB1; kB1 = kn;
            }
            if (actA) {
                const float kn = c1A * (nb1 + kA1) - c2A * nb2;
                kA2 = kA1; kA1 = kn;
            }
            // c1A unchanged on odd steps; c1B==c1A already holds.
        }
    }

    // K[126][126] lives in column jB=126 -> thread p = 62
    if (p == NQ - 1) {
        out[a * 32 + b] = kB1;
    }
}

extern "C" void kernel_launch(void* const* d_in, const int* in_sizes, int n_in,
                              void* d_out, int out_size, void* d_ws, size_t ws_size,
                              hipStream_t stream)
{
    const float* xs = (const float*)d_in[0];
    const float* ys = (const float*)d_in[1];
    float* out = (float*)d_out;

    dim3 grid(32, 32, 1);   // x = b, y = a
    dim3 block(64, 1, 1);
    hipLaunchKernelGGL(sig_pde_kernel, grid, block, 0, stream, xs, ys, out);
}

// Round 2
// 21.850 us; speedup vs baseline: 1.6802x; 1.6802x over previous
//
#include <hip/hip_runtime.h>

// Signature kernel via Goursat PDE, dyadic_order=1.
// xs: (32,64,16) f32, ys: (32,64,16) f32 -> out: (32,32) f32.
//
// inc[l,m] = <dx_l, dy_m>/4 ;  vf[i,j] = inc[i>>1, j>>1]  (126x126)
// K[r][c] = c1*(K[r][c-1]+K[r-1][c]) - c2*K[r-1][c-1], K[0][*]=K[*][0]=1
// c1 = 1 + v/2 + v^2/12, c2 = 1 - v^2/12.  Output = K[126][126].
//
// One wave per (a,b) pair, anti-diagonal wavefront. Thread p owns columns
// jA=2p+1, jB=2p+2. This revision removes the two latency hogs from the
// 252-step dependent chain:
//  - all c1/c2 precomputed into LDS coef[q][p] (throughput-bound pre-pass),
//    fetched in the scan via a depth-3 register prefetch pipeline
//  - neighbor exchange via DPP wave_shr:1 (VALU) instead of ds_bpermute
//  - fully branchless (cndmask selects)

#define NL 64
#define ND 16
#define NQ 63       // increments
#define SDX_STR 20  // sdx row stride (floats); 20 mod 32 -> conflict-free b128
#define CO_STR 64   // coef row stride (float2); -126p = 2p mod 32 -> 2-way (free)

__device__ __forceinline__ float dpp_shr1(float x) {
    // lane i <- lane i-1 ; lane 0 <- 0 (bound_ctrl), overridden by caller
    int r = __builtin_amdgcn_update_dpp(0, __float_as_int(x), 0x138, 0xf, 0xf, true);
    return __int_as_float(r);
}

__global__ void __launch_bounds__(64)
sig_pde_kernel(const float* __restrict__ xs,
               const float* __restrict__ ys,
               float* __restrict__ out)
{
    __shared__ float  sdx[NQ * SDX_STR];
    __shared__ float2 coef[NQ * CO_STR];

    const int a = blockIdx.y;
    const int b = blockIdx.x;
    const int p = threadIdx.x;

    const float* xa = xs + a * (NL * ND);
    const float* yb = ys + b * (NL * ND);

    float4 dy0, dy1, dy2, dy3;
    dy0 = dy1 = dy2 = dy3 = make_float4(0.f, 0.f, 0.f, 0.f);

    if (p < NQ) {
        const float4* x0 = reinterpret_cast<const float4*>(xa + p * ND);
        const float4* x1 = reinterpret_cast<const float4*>(xa + (p + 1) * ND);
        float* dst = &sdx[p * SDX_STR];
#pragma unroll
        for (int e = 0; e < 4; ++e) {
            float4 u = x1[e], v = x0[e];
            *reinterpret_cast<float4*>(dst + 4 * e) =
                make_float4(u.x - v.x, u.y - v.y, u.z - v.z, u.w - v.w);
        }
        const float4* y0 = reinterpret_cast<const float4*>(yb + p * ND);
        const float4* y1 = reinterpret_cast<const float4*>(yb + (p + 1) * ND);
        float4 s, t;
        s = y0[0]; t = y1[0]; dy0 = make_float4(t.x - s.x, t.y - s.y, t.z - s.z, t.w - s.w);
        s = y0[1]; t = y1[1]; dy1 = make_float4(t.x - s.x, t.y - s.y, t.z - s.z, t.w - s.w);
        s = y0[2]; t = y1[2]; dy2 = make_float4(t.x - s.x, t.y - s.y, t.z - s.z, t.w - s.w);
        s = y0[3]; t = y1[3]; dy3 = make_float4(t.x - s.x, t.y - s.y, t.z - s.z, t.w - s.w);
    }
    __syncthreads();

    // ---- pre-pass: c1,c2 for every q, this thread's dy ----
    if (p < NQ) {
#pragma unroll 4
        for (int q = 0; q < NQ; ++q) {
            const float* dxr = &sdx[q * SDX_STR];
            float4 a0 = *reinterpret_cast<const float4*>(dxr);
            float4 a1 = *reinterpret_cast<const float4*>(dxr + 4);
            float4 a2 = *reinterpret_cast<const float4*>(dxr + 8);
            float4 a3 = *reinterpret_cast<const float4*>(dxr + 12);
            float dot = a0.x * dy0.x + a0.y * dy0.y + a0.z * dy0.z + a0.w * dy0.w
                      + a1.x * dy1.x + a1.y * dy1.y + a1.z * dy1.z + a1.w * dy1.w
                      + a2.x * dy2.x + a2.y * dy2.y + a2.z * dy2.z + a2.w * dy2.w
                      + a3.x * dy3.x + a3.y * dy3.y + a3.z * dy3.z + a3.w * dy3.w;
            const float v  = 0.25f * dot;
            const float v2 = v * v * (1.0f / 12.0f);
            coef[q * CO_STR + p] = make_float2(1.f + 0.5f * v + v2, 1.f - v2);
        }
    }
    __syncthreads();

    // ---- wavefront scan ----
    const int pp = (p < NQ) ? p : (NQ - 1);
    auto ldc = [&](int q) -> float2 {
        int qc = q < 0 ? 0 : (q > NQ - 1 ? NQ - 1 : q);
        return coef[qc * CO_STR + pp];
    };

    float kA1 = 1.f, kA2 = 1.f, kB1 = 1.f, kB2 = 1.f;
    float c1B = 1.f, c2B = 1.f;   // B's even-step coeffs = prev iteration's cb0
    const bool p0 = (p == 0);

    float2 cb0 = ldc(0 - p);
    float2 cb1 = ldc(1 - p);
    float2 cb2 = ldc(2 - p);

#pragma unroll 3
    for (int tt = 0; tt < 126; ++tt) {
        float2 cbn = ldc(tt + 3 - p);           // depth-3 prefetch
        const int d = tt - p;                   // q index for column pair
        const bool aA  = (unsigned)d <= 62u;        // A active (both substeps)
        const bool aBe = (unsigned)(d - 1) <= 62u;  // B active, even substep

        // ---- even substep (rA = 1+2d, new coefficient row) ----
        {
            float nb1 = dpp_shr1(kB1); nb1 = p0 ? 1.f : nb1;
            float nb2 = dpp_shr1(kB2); nb2 = p0 ? 1.f : nb2;
            const float knB = c1B * (kA1 + kB1) - c2B * kA2;    // pre-update kA
            const float knA = cb0.x * (nb1 + kA1) - cb0.y * nb2;
            kB2 = aBe ? kB1 : kB2;  kB1 = aBe ? knB : kB1;
            kA2 = aA  ? kA1 : kA2;  kA1 = aA  ? knA : kA1;
        }
        // ---- odd substep (rA = 2+2d, same coefficient row for A and B) ----
        {
            float nb1 = dpp_shr1(kB1); nb1 = p0 ? 1.f : nb1;
            float nb2 = dpp_shr1(kB2); nb2 = p0 ? 1.f : nb2;
            const float knB = cb0.x * (kA1 + kB1) - cb0.y * kA2;
            const float knA = cb0.x * (nb1 + kA1) - cb0.y * nb2;
            kB2 = aA ? kB1 : kB2;  kB1 = aA ? knB : kB1;
            kA2 = aA ? kA1 : kA2;  kA1 = aA ? knA : kA1;
        }
        c1B = cb0.x; c2B = cb0.y;
        cb0 = cb1; cb1 = cb2; cb2 = cbn;
    }

    // K[126][126] lives in column jB = 126 -> thread p = 62
    if (p == NQ - 1) {
        out[a * 32 + b] = kB1;
    }
}

extern "C" void kernel_launch(void* const* d_in, const int* in_sizes, int n_in,
                              void* d_out, int out_size, void* d_ws, size_t ws_size,
                              hipStream_t stream)
{
    const float* xs = (const float*)d_in[0];
    const float* ys = (const float*)d_in[1];
    float* out = (float*)d_out;

    dim3 grid(32, 32, 1);   // x = b, y = a
    dim3 block(64, 1, 1);
    hipLaunchKernelGGL(sig_pde_kernel, grid, block, 0, stream, xs, ys, out);
}

// Round 3
// 20.435 us; speedup vs baseline: 1.7965x; 1.0692x over previous
//
#include <hip/hip_runtime.h>

// Signature kernel via Goursat PDE, dyadic_order=1.
// xs: (32,64,16) f32, ys: (32,64,16) f32 -> out: (32,32) f32.
//
// inc[l,m] = <dx_l, dy_m>/4 ;  vf[i,j] = inc[i>>1, j>>1]  (126x126)
// K[r][c] = c1*(K[r][c-1]+K[r-1][c]) - c2*K[r-1][c-1], K[0][*]=K[*][0]=1
// c1 = 1 + v/2 + v^2/12, c2 = 1 - v^2/12.  Output = K[126][126].
//
// One wave per (a,b) pair, anti-diagonal wavefront; thread p owns columns
// jA=2p+1, jB=2p+2. 1 wave/SIMD -> issue-bound: this revision minimizes
// instructions/iteration:
//  - coef rows padded with (0.5, 0): identity update on the all-ones
//    leading edge -> A commits unmasked, only B needs masks (2 cmp + 4 sel)
//  - DPP wave_shr:1 with old=1.0 (bound_ctrl=false): lane0 boundary free
//  - single-clamp prefetch index, depth-3 LDS pipeline

#define NL 64
#define ND 16
#define NQ 63
#define SDX_STR 20   // 20 mod 32 -> conflict-free b128 (but reads are broadcast anyway)
#define CO_STR 64    // float2 row stride; lane offset 2p mod 32 -> 2-way (free)

__device__ __forceinline__ float dpp_shr1_old1(float x, float one) {
    // lane i <- lane i-1 ; lane 0 <- `one` (old kept, bound_ctrl=false)
    int r = __builtin_amdgcn_update_dpp(__float_as_int(one), __float_as_int(x),
                                        0x138, 0xf, 0xf, false);
    return __int_as_float(r);
}

__global__ void __launch_bounds__(64)
sig_pde_kernel(const float* __restrict__ xs,
               const float* __restrict__ ys,
               float* __restrict__ out)
{
    __shared__ float  sdx[NQ * SDX_STR];
    __shared__ float2 coef[65 * CO_STR];   // row 0 and row 64 are (0.5,0) padding

    const int a = blockIdx.y;
    const int b = blockIdx.x;
    const int p = threadIdx.x;

    const float* xa = xs + a * (NL * ND);
    const float* yb = ys + b * (NL * ND);

    float4 dy0, dy1, dy2, dy3;
    dy0 = dy1 = dy2 = dy3 = make_float4(0.f, 0.f, 0.f, 0.f);

    if (p < NQ) {
        const float4* x0 = reinterpret_cast<const float4*>(xa + p * ND);
        const float4* x1 = reinterpret_cast<const float4*>(xa + (p + 1) * ND);
        float* dst = &sdx[p * SDX_STR];
#pragma unroll
        for (int e = 0; e < 4; ++e) {
            float4 u = x1[e], v = x0[e];
            *reinterpret_cast<float4*>(dst + 4 * e) =
                make_float4(u.x - v.x, u.y - v.y, u.z - v.z, u.w - v.w);
        }
        const float4* y0 = reinterpret_cast<const float4*>(yb + p * ND);
        const float4* y1 = reinterpret_cast<const float4*>(yb + (p + 1) * ND);
        float4 s, t;
        s = y0[0]; t = y1[0]; dy0 = make_float4(t.x - s.x, t.y - s.y, t.z - s.z, t.w - s.w);
        s = y0[1]; t = y1[1]; dy1 = make_float4(t.x - s.x, t.y - s.y, t.z - s.z, t.w - s.w);
        s = y0[2]; t = y1[2]; dy2 = make_float4(t.x - s.x, t.y - s.y, t.z - s.z, t.w - s.w);
        s = y0[3]; t = y1[3]; dy3 = make_float4(t.x - s.x, t.y - s.y, t.z - s.z, t.w - s.w);
    }
    // padding rows (identity-update coefficients)
    coef[0 * CO_STR + p]  = make_float2(0.5f, 0.f);
    coef[64 * CO_STR + p] = make_float2(0.5f, 0.f);
    __syncthreads();

    // ---- pre-pass: c1,c2 for every q (all 64 lanes; lane 63 forced to padding) ----
#pragma unroll 7
    for (int q = 0; q < NQ; ++q) {
        const float* dxr = &sdx[q * SDX_STR];
        float4 a0 = *reinterpret_cast<const float4*>(dxr);
        float4 a1 = *reinterpret_cast<const float4*>(dxr + 4);
        float4 a2 = *reinterpret_cast<const float4*>(dxr + 8);
        float4 a3 = *reinterpret_cast<const float4*>(dxr + 12);
        float dot = a0.x * dy0.x + a0.y * dy0.y + a0.z * dy0.z + a0.w * dy0.w
                  + a1.x * dy1.x + a1.y * dy1.y + a1.z * dy1.z + a1.w * dy1.w
                  + a2.x * dy2.x + a2.y * dy2.y + a2.z * dy2.z + a2.w * dy2.w
                  + a3.x * dy3.x + a3.y * dy3.y + a3.z * dy3.z + a3.w * dy3.w;
        const float v  = 0.25f * dot;
        const float v2 = v * v * (1.0f / 12.0f);
        float c1 = 1.f + 0.5f * v + v2;
        float c2 = 1.f - v2;
        if (p >= NQ) { c1 = 0.5f; c2 = 0.f; }   // lane 63: keep padding semantics
        coef[(q + 1) * CO_STR + p] = make_float2(c1, c2);
    }
    __syncthreads();

    // ---- wavefront scan ----
    const float one = 1.0f;
    float kA1 = 1.f, kA2 = 1.f, kB1 = 1.f, kB2 = 1.f;
    float c1B = 0.5f, c2B = 0.f;            // "cb0 of iteration -1" = padding

    const float2* cp = &coef[p];            // lane-column base
    auto ldrow = [&](int q1) -> float2 {    // q1 = d+1 for the target iteration
        int rc = q1 < 0 ? 0 : (q1 > 64 ? 64 : q1);
        return cp[rc * CO_STR];
    };

    float2 cb0 = ldrow(1 - p);
    float2 cb1 = ldrow(2 - p);
    float2 cb2 = ldrow(3 - p);

#pragma unroll 6
    for (int tt = 0; tt < 126; ++tt) {
        float2 cbn = ldrow(tt + 4 - p);     // depth-3 prefetch (row for d = tt+3-p)
        const int d = tt - p;
        const bool mE = d <= 63;            // B even-substep commit (rows 2..126)
        const bool mO = d <= 62;            // B odd-substep commit (rows 1..125)

        // ---- even substep: A row 2d+1 (coef cb0), B row 2d (coef c1B/c2B) ----
        {
            const float t0  = kA1 + kB1;
            const float u0  = c2B * kA2;
            const float nb1 = dpp_shr1_old1(kB1, one);
            const float nb2 = dpp_shr1_old1(kB2, one);
            const float knB = __builtin_fmaf(c1B, t0, -u0);
            const float t1  = nb1 + kA1;
            const float u1  = cb0.y * nb2;
            const float knA = __builtin_fmaf(cb0.x, t1, -u1);
            kB2 = mE ? kB1 : kB2;
            kB1 = mE ? knB : kB1;
            kA2 = kA1;
            kA1 = knA;                       // unmasked: padding keeps edge at 1
        }
        // ---- odd substep: A row 2d+2, B row 2d+1 (both coef cb0) ----
        {
            const float t0  = kA1 + kB1;
            const float u0  = cb0.y * kA2;
            const float nb1 = dpp_shr1_old1(kB1, one);
            const float nb2 = dpp_shr1_old1(kB2, one);
            const float knB = __builtin_fmaf(cb0.x, t0, -u0);
            const float t1  = nb1 + kA1;
            const float u1  = cb0.y * nb2;
            const float knA = __builtin_fmaf(cb0.x, t1, -u1);
            kB2 = mO ? kB1 : kB2;
            kB1 = mO ? knB : kB1;
            kA2 = kA1;
            kA1 = knA;
        }
        c1B = cb0.x; c2B = cb0.y;
        cb0 = cb1; cb1 = cb2; cb2 = cbn;
    }

    // K[126][126] = column jB=126 (lane 62) after its d=63 even-substep commit
    if (p == NQ - 1) {
        out[a * 32 + b] = kB1;
    }
}

extern "C" void kernel_launch(void* const* d_in, const int* in_sizes, int n_in,
                              void* d_out, int out_size, void* d_ws, size_t ws_size,
                              hipStream_t stream)
{
    const float* xs = (const float*)d_in[0];
    const float* ys = (const float*)d_in[1];
    float* out = (float*)d_out;

    dim3 grid(32, 32, 1);   // x = b, y = a
    dim3 block(64, 1, 1);
    hipLaunchKernelGGL(sig_pde_kernel, grid, block, 0, stream, xs, ys, out);
}

// Round 4
// 18.006 us; speedup vs baseline: 2.0389x; 1.1349x over previous
//
#include <hip/hip_runtime.h>

// Signature kernel via Goursat PDE, dyadic_order=1.
// xs: (32,64,16) f32, ys: (32,64,16) f32 -> out: (32,32) f32.
//
// inc[l,m] = <dx_l, dy_m>/4 ;  vf[i,j] = inc[i>>1, j>>1]  (126x126)
// K[r][c] = c1*(K[r][c-1]+K[r-1][c]) - c2*K[r-1][c-1], K[0][*]=K[*][0]=1
// c1 = 1 + v/2 + v^2/12, c2 = 1 - v^2/12.  Output = K[126][126].
//
// One wave per (a,b) pair. 2x2-BLOCK wavefront: vf is constant over each
// 2x2 cell block (dyadic refinement), and thread p's columns 2p+1,2p+2
// share q_col=p, so block (d,p) (rows 2d+1..2d+2) uses ONE (c1,c2).
// Block time T = d+p, T = 0..124 -> 125 steps (was 252 substeps).
// Neighbor lane p-1 computed block (d, p-1) at T-1; exports via DPP:
//   bT = K[2d][2p] (its pre-step kB1), bM = K[2d+1][2p], kB1 = K[2d+2][2p].
// Padding coef rows (0.5, 0) make out-of-band steps identity on the
// all-ones leading edge -> NO masks anywhere in the scan.

#define NL 64
#define ND 16
#define NQ 63
#define SDX_STR 20   // floats; 20 mod 32 -> conflict-free b128
#define CO_STR 64    // float2 row stride; lane offset 2p mod 32 -> 2-way (free)

__device__ __forceinline__ float dpp_shr1_old1(float x, float one) {
    // lane i <- lane i-1 ; lane 0 <- `one` (old kept, bound_ctrl=false)
    int r = __builtin_amdgcn_update_dpp(__float_as_int(one), __float_as_int(x),
                                        0x138, 0xf, 0xf, false);
    return __int_as_float(r);
}

__global__ void __launch_bounds__(64)
sig_pde_kernel(const float* __restrict__ xs,
               const float* __restrict__ ys,
               float* __restrict__ out)
{
    __shared__ float  sdx[NQ * SDX_STR];
    __shared__ float2 coef[65 * CO_STR];   // rows 0 and 64 are (0.5, 0) padding

    const int a = blockIdx.y;
    const int b = blockIdx.x;
    const int p = threadIdx.x;

    const float* xa = xs + a * (NL * ND);
    const float* yb = ys + b * (NL * ND);

    float4 dy0, dy1, dy2, dy3;
    dy0 = dy1 = dy2 = dy3 = make_float4(0.f, 0.f, 0.f, 0.f);

    if (p < NQ) {
        const float4* x0 = reinterpret_cast<const float4*>(xa + p * ND);
        const float4* x1 = reinterpret_cast<const float4*>(xa + (p + 1) * ND);
        float* dst = &sdx[p * SDX_STR];
#pragma unroll
        for (int e = 0; e < 4; ++e) {
            float4 u = x1[e], v = x0[e];
            *reinterpret_cast<float4*>(dst + 4 * e) =
                make_float4(u.x - v.x, u.y - v.y, u.z - v.z, u.w - v.w);
        }
        const float4* y0 = reinterpret_cast<const float4*>(yb + p * ND);
        const float4* y1 = reinterpret_cast<const float4*>(yb + (p + 1) * ND);
        float4 s, t;
        s = y0[0]; t = y1[0]; dy0 = make_float4(t.x - s.x, t.y - s.y, t.z - s.z, t.w - s.w);
        s = y0[1]; t = y1[1]; dy1 = make_float4(t.x - s.x, t.y - s.y, t.z - s.z, t.w - s.w);
        s = y0[2]; t = y1[2]; dy2 = make_float4(t.x - s.x, t.y - s.y, t.z - s.z, t.w - s.w);
        s = y0[3]; t = y1[3]; dy3 = make_float4(t.x - s.x, t.y - s.y, t.z - s.z, t.w - s.w);
    }
    // padding rows (identity-update coefficients)
    coef[0 * CO_STR + p]  = make_float2(0.5f, 0.f);
    coef[64 * CO_STR + p] = make_float2(0.5f, 0.f);
    __syncthreads();

    // ---- pre-pass: coef[q+1][p] = (c1,c2) for v = <dx_q, dy_p>/4 ----
#pragma unroll 7
    for (int q = 0; q < NQ; ++q) {
        const float* dxr = &sdx[q * SDX_STR];
        float4 a0 = *reinterpret_cast<const float4*>(dxr);
        float4 a1 = *reinterpret_cast<const float4*>(dxr + 4);
        float4 a2 = *reinterpret_cast<const float4*>(dxr + 8);
        float4 a3 = *reinterpret_cast<const float4*>(dxr + 12);
        float dot = a0.x * dy0.x + a0.y * dy0.y + a0.z * dy0.z + a0.w * dy0.w
                  + a1.x * dy1.x + a1.y * dy1.y + a1.z * dy1.z + a1.w * dy1.w
                  + a2.x * dy2.x + a2.y * dy2.y + a2.z * dy2.z + a2.w * dy2.w
                  + a3.x * dy3.x + a3.y * dy3.y + a3.z * dy3.z + a3.w * dy3.w;
        const float v  = 0.25f * dot;
        const float v2 = v * v * (1.0f / 12.0f);
        float c1 = 1.f + 0.5f * v + v2;
        float c2 = 1.f - v2;
        if (p >= NQ) { c1 = 0.5f; c2 = 0.f; }   // lane 63: padding semantics
        coef[(q + 1) * CO_STR + p] = make_float2(c1, c2);
    }
    __syncthreads();

    // ---- 2x2-block wavefront scan, 125 steps ----
    const float one = 1.0f;
    float kA1 = 1.f;   // own bottom-left  state: K[2d][2p+1] entering step
    float kB1 = 1.f;   // own bottom-right state: K[2d][2p+2] entering step
    float bT  = 1.f;   // export: pre-step kB1 of PREVIOUS step  = K[2d][2p+2 -> neighbor's 2p]
    float bM  = 1.f;   // export: a12 of previous step           = K[2d+1][..]

    const float2* cp = &coef[p];
    auto ldrow = [&](int q1) -> float2 {   // q1 = d+1, clamped to [0,64]
        int rc = q1 < 0 ? 0 : (q1 > 64 ? 64 : q1);
        return cp[rc * CO_STR];
    };

    float2 cb0 = ldrow(1 - p);   // row for T=0 (d = -p)
    float2 cb1 = ldrow(2 - p);
    float2 cb2 = ldrow(3 - p);

#pragma unroll 5
    for (int T = 0; T < 125; ++T) {
        float2 cbn = ldrow(T + 4 - p);     // depth-3 prefetch
        // neighbor exports (lane p-1's step T-1 block, same d):
        const float nbT = dpp_shr1_old1(bT,  one);   // K[2d  ][2p]
        const float nbM = dpp_shr1_old1(bM,  one);   // K[2d+1][2p]
        const float nbB = dpp_shr1_old1(kB1, one);   // K[2d+2][2p]
        const float c1 = cb0.x, c2 = cb0.y;

        const float a11 = __builtin_fmaf(c1, nbM + kA1, -(c2 * nbT));
        const float a12 = __builtin_fmaf(c1, a11 + kB1, -(c2 * kA1));
        const float a21 = __builtin_fmaf(c1, nbB + a11, -(c2 * nbM));
        const float a22 = __builtin_fmaf(c1, a21 + a12, -(c2 * a11));

        bT = kB1;            // pre-step top-right becomes next step's T-export
        bM = a12;
        kA1 = a21;
        kB1 = a22;

        cb0 = cb1; cb1 = cb2; cb2 = cbn;
    }

    // K[126][126] = a22 of block (62,62), computed by lane 62 at T=124
    if (p == 62) {
        out[a * 32 + b] = kB1;
    }
}

extern "C" void kernel_launch(void* const* d_in, const int* in_sizes, int n_in,
                              void* d_out, int out_size, void* d_ws, size_t ws_size,
                              hipStream_t stream)
{
    const float* xs = (const float*)d_in[0];
    const float* ys = (const float*)d_in[1];
    float* out = (float*)d_out;

    dim3 grid(32, 32, 1);   // x = b, y = a
    dim3 block(64, 1, 1);
    hipLaunchKernelGGL(sig_pde_kernel, grid, block, 0, stream, xs, ys, out);
}

// Round 5
// 16.227 us; speedup vs baseline: 2.2624x; 1.1096x over previous
//
#include <hip/hip_runtime.h>

// Signature kernel via Goursat PDE, dyadic_order=1.
// xs: (32,64,16) f32, ys: (32,64,16) f32 -> out: (32,32) f32.
//
// inc[l,m] = <dx_l, dy_m>/4 ;  vf[i,j] = inc[i>>1, j>>1]  (126x126)
// K[r][c] = c1*(K[r][c-1]+K[r-1][c]) - c2*K[r-1][c-1], K[0][*]=K[*][0]=1
// c1 = 1 + v/2 + v^2/12, c2 = 1 - v^2/12.  Output = K[126][126].
//
// One wave per (a,b) pair, 2x2-block wavefront (block d = T - p, lane p owns
// cols 2p+1,2p+2; one (c1,c2) per block since vf is 2x2-constant).
// This revision (issue-bound, 1 wave/SIMD):
//  - 2 DPP/step: receiver caches last step's shr1(kB1) as this step's nbT
//  - one-instruction unsigned clamp (rows 0 and 64 are identical padding)
//  - no barrier between pre-pass and scan (lane p only reads coef column p;
//    same-wave DS ops are in-order)
//  - pre-pass dot via v_pk_fma_f32 (packed 2xf32, VOP3P)

#define NL 64
#define ND 16
#define NQ 63
#define SDX_STR 20   // floats; 20 mod 32 -> conflict-free b128
#define CO_STR 64    // float2 row stride; lane offset 2p mod 32 -> 2-way (free)

__device__ __forceinline__ float dpp_shr1_old1(float x, float one) {
    // lane i <- lane i-1 ; lane 0 <- `one` (old kept, bound_ctrl=false)
    int r = __builtin_amdgcn_update_dpp(__float_as_int(one), __float_as_int(x),
                                        0x138, 0xf, 0xf, false);
    return __int_as_float(r);
}

__device__ __forceinline__ float2 pk_mul(float2 a, float2 b) {
    float2 d;
    asm("v_pk_mul_f32 %0, %1, %2" : "=v"(d) : "v"(a), "v"(b));
    return d;
}
__device__ __forceinline__ float2 pk_fma(float2 a, float2 b, float2 c) {
    float2 d;
    asm("v_pk_fma_f32 %0, %1, %2, %3" : "=v"(d) : "v"(a), "v"(b), "v"(c));
    return d;
}

__global__ void __launch_bounds__(64)
sig_pde_kernel(const float* __restrict__ xs,
               const float* __restrict__ ys,
               float* __restrict__ out)
{
    __shared__ float  sdx[NQ * SDX_STR];
    __shared__ float2 coef[65 * CO_STR];   // rows 0 and 64 are (0.5, 0) padding

    const int a = blockIdx.y;
    const int b = blockIdx.x;
    const int p = threadIdx.x;

    const float* xa = xs + a * (NL * ND);
    const float* yb = ys + b * (NL * ND);

    float2 d0, d1, d2, d3, d4, d5, d6, d7;
    d0 = d1 = d2 = d3 = d4 = d5 = d6 = d7 = make_float2(0.f, 0.f);

    if (p < NQ) {
        const float4* x0 = reinterpret_cast<const float4*>(xa + p * ND);
        const float4* x1 = reinterpret_cast<const float4*>(xa + (p + 1) * ND);
        float* dst = &sdx[p * SDX_STR];
#pragma unroll
        for (int e = 0; e < 4; ++e) {
            float4 u = x1[e], v = x0[e];
            *reinterpret_cast<float4*>(dst + 4 * e) =
                make_float4(u.x - v.x, u.y - v.y, u.z - v.z, u.w - v.w);
        }
        const float4* y0 = reinterpret_cast<const float4*>(yb + p * ND);
        const float4* y1 = reinterpret_cast<const float4*>(yb + (p + 1) * ND);
        float4 s, t;
        s = y0[0]; t = y1[0]; d0 = make_float2(t.x - s.x, t.y - s.y); d1 = make_float2(t.z - s.z, t.w - s.w);
        s = y0[1]; t = y1[1]; d2 = make_float2(t.x - s.x, t.y - s.y); d3 = make_float2(t.z - s.z, t.w - s.w);
        s = y0[2]; t = y1[2]; d4 = make_float2(t.x - s.x, t.y - s.y); d5 = make_float2(t.z - s.z, t.w - s.w);
        s = y0[3]; t = y1[3]; d6 = make_float2(t.x - s.x, t.y - s.y); d7 = make_float2(t.z - s.z, t.w - s.w);
    }
    // padding rows (identity-update coefficients)
    coef[0 * CO_STR + p]  = make_float2(0.5f, 0.f);
    coef[64 * CO_STR + p] = make_float2(0.5f, 0.f);
    __syncthreads();   // sdx must be visible to all lanes for the pre-pass

    // ---- pre-pass: coef[q+1][p] = (c1,c2) for v = <dx_q, dy_p>/4 ----
    // (lane 63: dy = 0 -> c1=1,c2=1; its column never escapes lane 63)
#pragma unroll 7
    for (int q = 0; q < NQ; ++q) {
        const float4* dx4 = reinterpret_cast<const float4*>(&sdx[q * SDX_STR]);
        float4 A0 = dx4[0], A1 = dx4[1], A2 = dx4[2], A3 = dx4[3];
        float2 acc = pk_mul(make_float2(A0.x, A0.y), d0);
        acc = pk_fma(make_float2(A0.z, A0.w), d1, acc);
        acc = pk_fma(make_float2(A1.x, A1.y), d2, acc);
        acc = pk_fma(make_float2(A1.z, A1.w), d3, acc);
        acc = pk_fma(make_float2(A2.x, A2.y), d4, acc);
        acc = pk_fma(make_float2(A2.z, A2.w), d5, acc);
        acc = pk_fma(make_float2(A3.x, A3.y), d6, acc);
        acc = pk_fma(make_float2(A3.z, A3.w), d7, acc);
        const float dot = acc.x + acc.y;
        const float v  = 0.25f * dot;
        const float v2 = v * v * (1.0f / 12.0f);
        const float c1 = __builtin_fmaf(0.5f, v, 1.f) + v2;
        const float c2 = 1.f - v2;
        coef[(q + 1) * CO_STR + p] = make_float2(c1, c2);
    }
    // NO barrier: the scan's lane p reads only coef column p, which lane p
    // itself wrote; same-wave DS ops complete in order.

    // ---- 2x2-block wavefront scan, 125 steps, 2 DPP/step ----
    const float one = 1.0f;
    float kA1 = 1.f;   // K[2d][2p+1] entering step
    float kB1 = 1.f;   // K[2d][2p+2] entering step
    float bM  = 1.f;   // a12 of previous step = K[2d-1][2p+2]
    float rx  = 1.f;   // prev step's shr1(kB1) = K[2d][2p] = nbT for this step

    auto ldrow = [&](int q1) -> float2 {
        // negatives wrap to huge unsigned -> clamp to 64; rows 0 and 64 both padding
        unsigned rc = (unsigned)q1 > 64u ? 64u : (unsigned)q1;
        return coef[rc * CO_STR + p];
    };

    float2 cb0 = ldrow(1 - p);   // row for T=0 (d = -p)
    float2 cb1 = ldrow(2 - p);
    float2 cb2 = ldrow(3 - p);

#pragma unroll 5
    for (int T = 0; T < 125; ++T) {
        float2 cbn = ldrow(T + 4 - p);               // depth-3 prefetch
        const float nbB = dpp_shr1_old1(kB1, one);   // K[2d+2][2p]
        const float nbM = dpp_shr1_old1(bM,  one);   // K[2d+1][2p]
        const float c1 = cb0.x, c2 = cb0.y;

        const float a11 = __builtin_fmaf(c1, nbM + kA1, -(c2 * rx));
        const float a12 = __builtin_fmaf(c1, a11 + kB1, -(c2 * kA1));
        const float a21 = __builtin_fmaf(c1, nbB + a11, -(c2 * nbM));
        const float a22 = __builtin_fmaf(c1, a21 + a12, -(c2 * a11));

        rx = nbB; bM = a12; kA1 = a21; kB1 = a22;
        cb0 = cb1; cb1 = cb2; cb2 = cbn;
    }

    // K[126][126] = a22 of block (62,62), lane 62 at T=124
    if (p == 62) {
        out[a * 32 + b] = kB1;
    }
}

extern "C" void kernel_launch(void* const* d_in, const int* in_sizes, int n_in,
                              void* d_out, int out_size, void* d_ws, size_t ws_size,
                              hipStream_t stream)
{
    const float* xs = (const float*)d_in[0];
    const float* ys = (const float*)d_in[1];
    float* out = (float*)d_out;

    dim3 grid(32, 32, 1);   // x = b, y = a
    dim3 block(64, 1, 1);
    hipLaunchKernelGGL(sig_pde_kernel, grid, block, 0, stream, xs, ys, out);
}

// Round 7
// 14.964 us; speedup vs baseline: 2.4533x; 1.0844x over previous
//
#include <hip/hip_runtime.h>

// Signature kernel via Goursat PDE, dyadic_order=1.
// xs: (32,64,16) f32, ys: (32,64,16) f32 -> out: (32,32) f32.
//
// inc[l,m] = <dx_l, dy_m>/4 ;  vf[i,j] = inc[i>>1, j>>1]  (126x126)
// K[r][c] = c1*(K[r][c-1]+K[r-1][c]) - c2*K[r-1][c-1], K[0][*]=K[*][0]=1
// c1 = 1 + v/2 + v^2/12, c2 = 1 - v^2/12.  Output = K[126][126].
//
// One wave per (a,b) pair, 2x2-block wavefront (block d = T - p, lane p owns
// cols 2p+1,2p+2). Issue-bound at 1 wave/SIMD and low DVFS clock:
//  - prefetch depth 5 == unroll 5: coefficient pipeline rotates by renaming
//  - dx/dy stored as f16 pairs, dot via v_dot2_f32_f16 (f32 accumulate,
//    coefficient math stays f32): 2 ds_read_b128/q instead of 4
//  - 2 DPP/step, unsigned-min clamp, no barrier after pre-pass (lane-local)

#define NL 64
#define ND 16
#define NQ 63
#define SDXH_STR 12  // int (=half2) stride per row: 48B, 16B-aligned
#define CO_STR 64    // float2 row stride; lane offset 2p mod 32 -> 2-way (free)

typedef _Float16 half2_t __attribute__((ext_vector_type(2)));

__device__ __forceinline__ half2_t cvt_pk_f16(float a, float b) {
    // cvt_pkrtz returns an __fp16 vector type; bit_cast to our _Float16 vec
    return __builtin_bit_cast(half2_t, __builtin_amdgcn_cvt_pkrtz(a, b));
}

__device__ __forceinline__ float dpp_shr1_old1(float x, float one) {
    // lane i <- lane i-1 ; lane 0 <- `one` (old kept, bound_ctrl=false)
    int r = __builtin_amdgcn_update_dpp(__float_as_int(one), __float_as_int(x),
                                        0x138, 0xf, 0xf, false);
    return __int_as_float(r);
}

__global__ void __launch_bounds__(64)
sig_pde_kernel(const float* __restrict__ xs,
               const float* __restrict__ ys,
               float* __restrict__ out)
{
    __shared__ int    sdxh[NQ * SDXH_STR];   // dx rows as 8 half2 (+pad)
    __shared__ float2 coef[65 * CO_STR];     // rows 0 and 64 are (0.5,0) padding

    const int a = blockIdx.y;
    const int b = blockIdx.x;
    const int p = threadIdx.x;

    const float* xa = xs + a * (NL * ND);
    const float* yb = ys + b * (NL * ND);

    // ---- staging: dx -> LDS (f16), dy -> registers (f16 pairs) ----
    half2_t hy0, hy1, hy2, hy3, hy4, hy5, hy6, hy7;
    hy0 = hy1 = hy2 = hy3 = hy4 = hy5 = hy6 = hy7 = half2_t(0);

    if (p < NQ) {
        const float4* x0 = reinterpret_cast<const float4*>(xa + p * ND);
        const float4* x1 = reinterpret_cast<const float4*>(xa + (p + 1) * ND);
        const float4* y0 = reinterpret_cast<const float4*>(yb + p * ND);
        const float4* y1 = reinterpret_cast<const float4*>(yb + (p + 1) * ND);
        int dxw[8];
#pragma unroll
        for (int e = 0; e < 4; ++e) {
            float4 u = x1[e], v = x0[e];
            dxw[2 * e]     = __builtin_bit_cast(int, cvt_pk_f16(u.x - v.x, u.y - v.y));
            dxw[2 * e + 1] = __builtin_bit_cast(int, cvt_pk_f16(u.z - v.z, u.w - v.w));
        }
        int4* dst = reinterpret_cast<int4*>(&sdxh[p * SDXH_STR]);
        dst[0] = make_int4(dxw[0], dxw[1], dxw[2], dxw[3]);
        dst[1] = make_int4(dxw[4], dxw[5], dxw[6], dxw[7]);
        float4 s, t;
        s = y0[0]; t = y1[0];
        hy0 = cvt_pk_f16(t.x - s.x, t.y - s.y);
        hy1 = cvt_pk_f16(t.z - s.z, t.w - s.w);
        s = y0[1]; t = y1[1];
        hy2 = cvt_pk_f16(t.x - s.x, t.y - s.y);
        hy3 = cvt_pk_f16(t.z - s.z, t.w - s.w);
        s = y0[2]; t = y1[2];
        hy4 = cvt_pk_f16(t.x - s.x, t.y - s.y);
        hy5 = cvt_pk_f16(t.z - s.z, t.w - s.w);
        s = y0[3]; t = y1[3];
        hy6 = cvt_pk_f16(t.x - s.x, t.y - s.y);
        hy7 = cvt_pk_f16(t.z - s.z, t.w - s.w);
    }
    // padding rows (identity-update coefficients)
    coef[0 * CO_STR + p]  = make_float2(0.5f, 0.f);
    coef[64 * CO_STR + p] = make_float2(0.5f, 0.f);
    __syncthreads();   // dx rows must be visible to all lanes

    // ---- pre-pass: coef[q+1][p] = (c1,c2) for v = <dx_q, dy_p>/4 ----
    // (lane 63: dy = 0 -> c1=1,c2=1; its column never escapes lane 63)
#pragma unroll 7
    for (int q = 0; q < NQ; ++q) {
        const int4* rw = reinterpret_cast<const int4*>(&sdxh[q * SDXH_STR]);
        int4 w0 = rw[0], w1 = rw[1];
        float dot = __builtin_amdgcn_fdot2(__builtin_bit_cast(half2_t, w0.x), hy0, 0.f,  false);
        dot = __builtin_amdgcn_fdot2(__builtin_bit_cast(half2_t, w0.y), hy1, dot, false);
        dot = __builtin_amdgcn_fdot2(__builtin_bit_cast(half2_t, w0.z), hy2, dot, false);
        dot = __builtin_amdgcn_fdot2(__builtin_bit_cast(half2_t, w0.w), hy3, dot, false);
        dot = __builtin_amdgcn_fdot2(__builtin_bit_cast(half2_t, w1.x), hy4, dot, false);
        dot = __builtin_amdgcn_fdot2(__builtin_bit_cast(half2_t, w1.y), hy5, dot, false);
        dot = __builtin_amdgcn_fdot2(__builtin_bit_cast(half2_t, w1.z), hy6, dot, false);
        dot = __builtin_amdgcn_fdot2(__builtin_bit_cast(half2_t, w1.w), hy7, dot, false);
        const float v  = 0.25f * dot;
        const float v2 = v * v * (1.0f / 12.0f);
        const float c1 = __builtin_fmaf(0.5f, v, 1.f) + v2;
        const float c2 = 1.f - v2;
        coef[(q + 1) * CO_STR + p] = make_float2(c1, c2);
    }
    // NO barrier: the scan's lane p reads only coef column p, which lane p
    // itself wrote; same-wave DS ops complete in order.

    // ---- 2x2-block wavefront scan, 125 steps, 2 DPP/step ----
    const float one = 1.0f;
    float kA1 = 1.f;   // K[2d][2p+1] entering step
    float kB1 = 1.f;   // K[2d][2p+2] entering step
    float bM  = 1.f;   // a12 of previous step = K[2d-1][2p+2]
    float rx  = 1.f;   // prev step's shr1(kB1) = K[2d][2p] = nbT for this step

    const float2* cp = &coef[p];
    auto ldrow = [&](int q1) -> float2 {
        // negatives wrap huge unsigned -> clamp to 64; rows 0/64 both padding
        unsigned rc = (unsigned)q1 > 64u ? 64u : (unsigned)q1;
        return cp[rc * CO_STR];
    };

    // depth-5 pipeline == unroll 5: rotation is pure renaming, no movs
    float2 cb0 = ldrow(1 - p);   // row for T=0 (d = -p)
    float2 cb1 = ldrow(2 - p);
    float2 cb2 = ldrow(3 - p);
    float2 cb3 = ldrow(4 - p);
    float2 cb4 = ldrow(5 - p);

#pragma unroll 5
    for (int T = 0; T < 125; ++T) {
        float2 cbn = ldrow(T + 6 - p);               // depth-5 prefetch
        const float nbB = dpp_shr1_old1(kB1, one);   // K[2d+2][2p]
        const float nbM = dpp_shr1_old1(bM,  one);   // K[2d+1][2p]
        const float c1 = cb0.x, c2 = cb0.y;

        const float a11 = __builtin_fmaf(c1, nbM + kA1, -(c2 * rx));
        const float a12 = __builtin_fmaf(c1, a11 + kB1, -(c2 * kA1));
        const float a21 = __builtin_fmaf(c1, nbB + a11, -(c2 * nbM));
        const float a22 = __builtin_fmaf(c1, a21 + a12, -(c2 * a11));

        rx = nbB; bM = a12; kA1 = a21; kB1 = a22;
        cb0 = cb1; cb1 = cb2; cb2 = cb3; cb3 = cb4; cb4 = cbn;
    }

    // K[126][126] = a22 of block (62,62), lane 62 at T=124
    if (p == 62) {
        out[a * 32 + b] = kB1;
    }
}

extern "C" void kernel_launch(void* const* d_in, const int* in_sizes, int n_in,
                              void* d_out, int out_size, void* d_ws, size_t ws_size,
                              hipStream_t stream)
{
    const float* xs = (const float*)d_in[0];
    const float* ys = (const float*)d_in[1];
    float* out = (float*)d_out;

    dim3 grid(32, 32, 1);   // x = b, y = a
    dim3 block(64, 1, 1);
    hipLaunchKernelGGL(sig_pde_kernel, grid, block, 0, stream, xs, ys, out);
}

// Round 8
// 13.627 us; speedup vs baseline: 2.6940x; 1.0981x over previous
//
#include <hip/hip_runtime.h>

// Signature kernel via Goursat PDE, dyadic_order=1.
// xs: (32,64,16) f32, ys: (32,64,16) f32 -> out: (32,32) f32.
//
// inc[l,m] = <dx_l, dy_m>/4 ;  vf[i,j] = inc[i>>1, j>>1]  (126x126)
// K[r][c] = c1*(K[r][c-1]+K[r-1][c]) - c2*K[r-1][c-1], K[0][*]=K[*][0]=1
// c1 = 1 + v/2 + v^2/12, c2 = 1 - v^2/12.  Output = K[126][126].
//
// One wave (= one 64-thread workgroup) per (a,b) pair.
// Pre-pass: coef table = DX(64x16) x DY^T(16x64) via 16x mfma_f32_16x16x32_f16
//   (K zero-padded 16->32), then per-value poly:
//   c1 = 1 + dot/8 + dot^2/192, c2 = 1 - dot^2/192.
// Scan: 2x2-block wavefront (block d = T - p, lane p owns cols 2p+1,2p+2),
//   125 steps, 2 DPP/step, depth-5 coef prefetch == unroll 5, branchless.
// LDS: dxh/dyh f16 staging (10 KB) OVERLAYS the coef array (33 KB total ->
//   4 workgroups/CU). Single-wave workgroups: barriers are cheap fences.

#define NL 64
#define ND 16
#define NQ 63
#define CO_STR 64          // float2 per coef row
#define XW 20              // 32-bit words per dxh/dyh row (16B-aligned, ~2-way banks)

typedef _Float16 f16x8 __attribute__((ext_vector_type(8)));
typedef float    f32x4 __attribute__((ext_vector_type(4)));
typedef _Float16 half2_t __attribute__((ext_vector_type(2)));

__device__ __forceinline__ half2_t cvt_pk_f16(float a, float b) {
    return __builtin_bit_cast(half2_t, __builtin_amdgcn_cvt_pkrtz(a, b));
}

__device__ __forceinline__ int pack_f16(float a, float b) {
    return __builtin_bit_cast(int, cvt_pk_f16(a, b));
}

__device__ __forceinline__ float dpp_shr1_old1(float x, float one) {
    // lane i <- lane i-1 ; lane 0 <- `one` (old kept, bound_ctrl=false)
    int r = __builtin_amdgcn_update_dpp(__float_as_int(one), __float_as_int(x),
                                        0x138, 0xf, 0xf, false);
    return __int_as_float(r);
}

__global__ void __launch_bounds__(64)
sig_pde_kernel(const float* __restrict__ xs,
               const float* __restrict__ ys,
               float* __restrict__ out)
{
    // coef[65][64] float2 = 33280 B; dxh (5120 B) + dyh (5120 B) overlay the
    // front of it (dead after the fragment loads; stores land afterwards).
    __shared__ __align__(16) char lds[65 * CO_STR * 8];
    float2* coef = reinterpret_cast<float2*>(lds);
    int*    dxw  = reinterpret_cast<int*>(lds);                 // 64 rows x XW
    int*    dyw  = reinterpret_cast<int*>(lds + 64 * XW * 4);   // 64 rows x XW

    const int a = blockIdx.y;
    const int b = blockIdx.x;
    const int p = threadIdx.x;

    const float* xa = xs + a * (NL * ND);
    const float* yb = ys + b * (NL * ND);

    // ---- staging: dx, dy rows -> LDS as f16 (row 63 = zeros; K 16..31 = 0) ----
    {
        const int  rlo  = (p < 62) ? p : 62;     // keep loads in-bounds
        const bool real = (p < NQ);
        const float4* x0 = reinterpret_cast<const float4*>(xa + rlo * ND);
        const float4* x1 = reinterpret_cast<const float4*>(xa + (rlo + 1) * ND);
        const float4* y0 = reinterpret_cast<const float4*>(yb + rlo * ND);
        const float4* y1 = reinterpret_cast<const float4*>(yb + (rlo + 1) * ND);
        int dwx[8], dwy[8];
#pragma unroll
        for (int e = 0; e < 4; ++e) {
            float4 u = x1[e], v = x0[e];
            dwx[2 * e]     = real ? pack_f16(u.x - v.x, u.y - v.y) : 0;
            dwx[2 * e + 1] = real ? pack_f16(u.z - v.z, u.w - v.w) : 0;
            float4 s = y0[e], t = y1[e];
            dwy[2 * e]     = real ? pack_f16(t.x - s.x, t.y - s.y) : 0;
            dwy[2 * e + 1] = real ? pack_f16(t.z - s.z, t.w - s.w) : 0;
        }
        int4* dx4 = reinterpret_cast<int4*>(&dxw[p * XW]);
        dx4[0] = make_int4(dwx[0], dwx[1], dwx[2], dwx[3]);
        dx4[1] = make_int4(dwx[4], dwx[5], dwx[6], dwx[7]);
        dx4[2] = make_int4(0, 0, 0, 0);          // K = 16..23
        dx4[3] = make_int4(0, 0, 0, 0);          // K = 24..31
        int4* dy4 = reinterpret_cast<int4*>(&dyw[p * XW]);
        dy4[0] = make_int4(dwy[0], dwy[1], dwy[2], dwy[3]);
        dy4[1] = make_int4(dwy[4], dwy[5], dwy[6], dwy[7]);
        dy4[2] = make_int4(0, 0, 0, 0);
        dy4[3] = make_int4(0, 0, 0, 0);
    }
    __syncthreads();

    // ---- fragment loads (A: DX rows, B: DY rows; 8 contiguous K per lane) ----
    const int g   = p >> 4;          // K-group: k = 8g..8g+7
    const int r16 = p & 15;          // row within 16-tile
    f16x8 Af0, Af1, Af2, Af3, Bf0, Bf1, Bf2, Bf3;
    {
        const int base = r16 * XW + 4 * g;       // word offset
        Af0 = __builtin_bit_cast(f16x8, *reinterpret_cast<const int4*>(&dxw[base]));
        Af1 = __builtin_bit_cast(f16x8, *reinterpret_cast<const int4*>(&dxw[base + 16 * XW]));
        Af2 = __builtin_bit_cast(f16x8, *reinterpret_cast<const int4*>(&dxw[base + 32 * XW]));
        Af3 = __builtin_bit_cast(f16x8, *reinterpret_cast<const int4*>(&dxw[base + 48 * XW]));
        Bf0 = __builtin_bit_cast(f16x8, *reinterpret_cast<const int4*>(&dyw[base]));
        Bf1 = __builtin_bit_cast(f16x8, *reinterpret_cast<const int4*>(&dyw[base + 16 * XW]));
        Bf2 = __builtin_bit_cast(f16x8, *reinterpret_cast<const int4*>(&dyw[base + 32 * XW]));
        Bf3 = __builtin_bit_cast(f16x8, *reinterpret_cast<const int4*>(&dyw[base + 48 * XW]));
    }
    __syncthreads();   // all frag loads done before stores clobber the overlay

    // row 0 padding (identity-update coefficients) — after loads (overlay!)
    coef[p] = make_float2(0.5f, 0.f);

    // ---- 16 MFMA tiles -> poly -> coef[q+1][pcol] ----
    // C layout: col = lane&15, row = (lane>>4)*4 + reg  ->
    //   q = 16*ti + 4*g + reg, pcol = 16*tj + r16
    {
        f16x8 Afs[4] = {Af0, Af1, Af2, Af3};
        f16x8 Bfs[4] = {Bf0, Bf1, Bf2, Bf3};
        float2* crow = coef + (4 * g + 1) * CO_STR + r16;
#pragma unroll
        for (int ti = 0; ti < 4; ++ti) {
#pragma unroll
            for (int tj = 0; tj < 4; ++tj) {
                f32x4 acc = {0.f, 0.f, 0.f, 0.f};
                acc = __builtin_amdgcn_mfma_f32_16x16x32_f16(Afs[ti], Bfs[tj], acc, 0, 0, 0);
#pragma unroll
                for (int r = 0; r < 4; ++r) {
                    const float dot = acc[r];
                    const float d2  = dot * dot;
                    const float c1  = __builtin_fmaf(d2, (1.f / 192.f),
                                      __builtin_fmaf(dot, 0.125f, 1.f));
                    const float c2  = __builtin_fmaf(d2, (-1.f / 192.f), 1.f);
                    crow[(16 * ti + r) * CO_STR + 16 * tj] = make_float2(c1, c2);
                }
            }
        }
    }
    __syncthreads();

    // ---- 2x2-block wavefront scan, 125 steps, 2 DPP/step ----
    const float one = 1.0f;
    float kA1 = 1.f;   // K[2d][2p+1] entering step
    float kB1 = 1.f;   // K[2d][2p+2] entering step
    float bM  = 1.f;   // a12 of previous step
    float rx  = 1.f;   // prev step's shr1(kB1) = K[2d][2p]

    const float2* cp = &coef[p];
    auto ldrow = [&](int q1) -> float2 {
        // negatives wrap huge unsigned -> clamp to 64 (row 64: q=63 -> (1,1),
        // also identity on the all-ones leading edge; junk stays bounded)
        unsigned rc = (unsigned)q1 > 64u ? 64u : (unsigned)q1;
        return cp[rc * CO_STR];
    };

    // depth-5 pipeline == unroll 5: rotation is pure renaming, no movs
    float2 cb0 = ldrow(1 - p);   // row for T=0 (d = -p)
    float2 cb1 = ldrow(2 - p);
    float2 cb2 = ldrow(3 - p);
    float2 cb3 = ldrow(4 - p);
    float2 cb4 = ldrow(5 - p);

#pragma unroll 5
    for (int T = 0; T < 125; ++T) {
        float2 cbn = ldrow(T + 6 - p);               // depth-5 prefetch
        const float nbB = dpp_shr1_old1(kB1, one);   // K[2d+2][2p]
        const float nbM = dpp_shr1_old1(bM,  one);   // K[2d+1][2p]
        const float c1 = cb0.x, c2 = cb0.y;

        const float a11 = __builtin_fmaf(c1, nbM + kA1, -(c2 * rx));
        const float a12 = __builtin_fmaf(c1, a11 + kB1, -(c2 * kA1));
        const float a21 = __builtin_fmaf(c1, nbB + a11, -(c2 * nbM));
        const float a22 = __builtin_fmaf(c1, a21 + a12, -(c2 * a11));

        rx = nbB; bM = a12; kA1 = a21; kB1 = a22;
        cb0 = cb1; cb1 = cb2; cb2 = cb3; cb3 = cb4; cb4 = cbn;
    }

    // K[126][126] = a22 of block (62,62), lane 62 at T=124
    if (p == 62) {
        out[a * 32 + b] = kB1;
    }
}

extern "C" void kernel_launch(void* const* d_in, const int* in_sizes, int n_in,
                              void* d_out, int out_size, void* d_ws, size_t ws_size,
                              hipStream_t stream)
{
    const float* xs = (const float*)d_in[0];
    const float* ys = (const float*)d_in[1];
    float* out = (float*)d_out;

    dim3 grid(32, 32, 1);   // x = b, y = a
    dim3 block(64, 1, 1);
    hipLaunchKernelGGL(sig_pde_kernel, grid, block, 0, stream, xs, ys, out);
}

// Round 9
// 13.559 us; speedup vs baseline: 2.7077x; 1.0051x over previous
//
#include <hip/hip_runtime.h>

// Signature kernel via Goursat PDE, dyadic_order=1.
// xs: (32,64,16) f32, ys: (32,64,16) f32 -> out: (32,32) f32.
//
// inc[l,m] = <dx_l, dy_m>/4 ;  vf[i,j] = inc[i>>1, j>>1]  (126x126)
// K[r][c] = c1*(K[r][c-1]+K[r-1][c]) - c2*K[r-1][c-1], K[0][*]=K[*][0]=1
// c1 = 1 + v/2 + v^2/12, c2 = 1 - v^2/12.  Output = K[126][126].
//
// One wave per (a,b) pair.
// Pre-pass: coef table = DX(64x16) x DY^T(16x64) via 16x mfma_f32_16x16x32_f16,
//   pk-paired poly (v_pk_fma_f32), stores via ds_write2_b32 imm offsets.
// Scan: 2x2-block wavefront, 125 steps, 2 DPP/step, depth-5 prefetch:
//   phase 1 (T<60): clamped row addressing (fill-safe)
//   phase 2 (60<=T<120): incremental byte address, 1 v_add/step (no lane is
//     in fill; drain reads of rows >=65 are OOB-garbage but provably never
//     reach valid cells)
//   epilogue (T=120..124): consume pipeline, no prefetch.

#define NL 64
#define ND 16
#define NQ 63
#define CO_STR 64          // float2 per coef row (512 B/row)
#define XW 20              // 32-bit words per dxh/dyh row

typedef _Float16 f16x8 __attribute__((ext_vector_type(8)));
typedef float    f32x4 __attribute__((ext_vector_type(4)));
typedef _Float16 half2_t __attribute__((ext_vector_type(2)));

__device__ __forceinline__ half2_t cvt_pk_f16(float a, float b) {
    return __builtin_bit_cast(half2_t, __builtin_amdgcn_cvt_pkrtz(a, b));
}
__device__ __forceinline__ int pack_f16(float a, float b) {
    return __builtin_bit_cast(int, cvt_pk_f16(a, b));
}
__device__ __forceinline__ float dpp_shr1_old1(float x, float one) {
    int r = __builtin_amdgcn_update_dpp(__float_as_int(one), __float_as_int(x),
                                        0x138, 0xf, 0xf, false);
    return __int_as_float(r);
}
__device__ __forceinline__ float2 pk_mul(float2 a, float2 b) {
    float2 d;
    asm("v_pk_mul_f32 %0, %1, %2" : "=v"(d) : "v"(a), "v"(b));
    return d;
}
__device__ __forceinline__ float2 pk_fma(float2 a, float2 b, float2 c) {
    float2 d;
    asm("v_pk_fma_f32 %0, %1, %2, %3" : "=v"(d) : "v"(a), "v"(b), "v"(c));
    return d;
}
template<int O0, int O1>
__device__ __forceinline__ void dsw2(int addr, float v0, float v1) {
    // two 4B stores at addr + 4*O0 / addr + 4*O1
    asm volatile("ds_write2_b32 %0, %1, %2 offset0:%3 offset1:%4"
                 :: "v"(addr), "v"(v0), "v"(v1), "i"(O0), "i"(O1) : "memory");
}

__global__ void __launch_bounds__(64)
sig_pde_kernel(const float* __restrict__ xs,
               const float* __restrict__ ys,
               float* __restrict__ out)
{
    // coef[65][64] float2 = 33280 B; dxh/dyh f16 staging overlays the front.
    __shared__ __align__(16) char lds[65 * CO_STR * 8];
    float2* coef = reinterpret_cast<float2*>(lds);
    int*    dxw  = reinterpret_cast<int*>(lds);                 // 64 rows x XW
    int*    dyw  = reinterpret_cast<int*>(lds + 64 * XW * 4);   // 64 rows x XW

    const int a = blockIdx.y;
    const int b = blockIdx.x;
    const int p = threadIdx.x;

    const float* xa = xs + a * (NL * ND);
    const float* yb = ys + b * (NL * ND);

    // ---- staging: dx, dy rows -> LDS as f16 (row 63 zeros; K 16..31 zeros) ----
    {
        const int  rlo  = (p < 62) ? p : 62;
        const bool real = (p < NQ);
        const float4* x0 = reinterpret_cast<const float4*>(xa + rlo * ND);
        const float4* x1 = reinterpret_cast<const float4*>(xa + (rlo + 1) * ND);
        const float4* y0 = reinterpret_cast<const float4*>(yb + rlo * ND);
        const float4* y1 = reinterpret_cast<const float4*>(yb + (rlo + 1) * ND);
        int dwx[8], dwy[8];
#pragma unroll
        for (int e = 0; e < 4; ++e) {
            float4 u = x1[e], v = x0[e];
            dwx[2 * e]     = real ? pack_f16(u.x - v.x, u.y - v.y) : 0;
            dwx[2 * e + 1] = real ? pack_f16(u.z - v.z, u.w - v.w) : 0;
            float4 s = y0[e], t = y1[e];
            dwy[2 * e]     = real ? pack_f16(t.x - s.x, t.y - s.y) : 0;
            dwy[2 * e + 1] = real ? pack_f16(t.z - s.z, t.w - s.w) : 0;
        }
        int4* dx4 = reinterpret_cast<int4*>(&dxw[p * XW]);
        dx4[0] = make_int4(dwx[0], dwx[1], dwx[2], dwx[3]);
        dx4[1] = make_int4(dwx[4], dwx[5], dwx[6], dwx[7]);
        dx4[2] = make_int4(0, 0, 0, 0);
        dx4[3] = make_int4(0, 0, 0, 0);
        int4* dy4 = reinterpret_cast<int4*>(&dyw[p * XW]);
        dy4[0] = make_int4(dwy[0], dwy[1], dwy[2], dwy[3]);
        dy4[1] = make_int4(dwy[4], dwy[5], dwy[6], dwy[7]);
        dy4[2] = make_int4(0, 0, 0, 0);
        dy4[3] = make_int4(0, 0, 0, 0);
    }
    __syncthreads();

    // ---- fragment loads (A: DX rows, B: DY rows; 8 contiguous K per lane) ----
    const int g   = p >> 4;          // K-group: k = 8g..8g+7
    const int r16 = p & 15;          // row within 16-tile
    f16x8 Af0, Af1, Af2, Af3, Bf0, Bf1, Bf2, Bf3;
    {
        const int base = r16 * XW + 4 * g;
        Af0 = __builtin_bit_cast(f16x8, *reinterpret_cast<const int4*>(&dxw[base]));
        Af1 = __builtin_bit_cast(f16x8, *reinterpret_cast<const int4*>(&dxw[base + 16 * XW]));
        Af2 = __builtin_bit_cast(f16x8, *reinterpret_cast<const int4*>(&dxw[base + 32 * XW]));
        Af3 = __builtin_bit_cast(f16x8, *reinterpret_cast<const int4*>(&dxw[base + 48 * XW]));
        Bf0 = __builtin_bit_cast(f16x8, *reinterpret_cast<const int4*>(&dyw[base]));
        Bf1 = __builtin_bit_cast(f16x8, *reinterpret_cast<const int4*>(&dyw[base + 16 * XW]));
        Bf2 = __builtin_bit_cast(f16x8, *reinterpret_cast<const int4*>(&dyw[base + 32 * XW]));
        Bf3 = __builtin_bit_cast(f16x8, *reinterpret_cast<const int4*>(&dyw[base + 48 * XW]));
    }
    __syncthreads();   // frag loads done before stores clobber the overlay

    // row 0 padding (identity-update coefficients)
    coef[p] = make_float2(0.5f, 0.f);

    // ---- 16 MFMA tiles -> pk-poly -> ds_write2 stores ----
    // C layout: col = lane&15, row = (lane>>4)*4 + reg ->
    //   q = 16*ti + 4*g + reg, pcol = 16*tj + r16
    {
        f16x8 Afs[4] = {Af0, Af1, Af2, Af3};
        f16x8 Bfs[4] = {Bf0, Bf1, Bf2, Bf3};
        const float2 K8  = {0.125f, 0.125f};
        const float2 K1  = {1.f, 1.f};
        const float2 KP  = {1.f / 192.f, 1.f / 192.f};
        const float2 KN  = {-1.f / 192.f, -1.f / 192.f};
        const int vbase = (4 * g + 1) * 512 + r16 * 8;   // byte addr of (q0+1, col r16)
#pragma unroll
        for (int ti = 0; ti < 4; ++ti) {
            const int va = vbase + ti * 8192;            // rows block (regs 0,1)
            const int vb = va + 1024;                    // rows block (regs 2,3)
#pragma unroll
            for (int tj = 0; tj < 4; ++tj) {
                f32x4 acc = {0.f, 0.f, 0.f, 0.f};
                acc = __builtin_amdgcn_mfma_f32_16x16x32_f16(Afs[ti], Bfs[tj], acc, 0, 0, 0);
                float2 dA = {acc[0], acc[1]};
                float2 dB = {acc[2], acc[3]};
                float2 d2A = pk_mul(dA, dA),      d2B = pk_mul(dB, dB);
                float2 inA = pk_fma(dA, K8, K1),  inB = pk_fma(dB, K8, K1);
                float2 c1A = pk_fma(d2A, KP, inA), c1B = pk_fma(d2B, KP, inB);
                float2 c2A = pk_fma(d2A, KN, K1),  c2B = pk_fma(d2B, KN, K1);
                // offsets in 4B units: col tj*16 cells = 128 B = 32 units;
                // next row = 512 B = 128 units. All <= 225 (8-bit field ok).
                if (tj == 0) {
                    dsw2<0,       1>(va, c1A.x, c2A.x);
                    dsw2<128,   129>(va, c1A.y, c2A.y);
                    dsw2<0,       1>(vb, c1B.x, c2B.x);
                    dsw2<128,   129>(vb, c1B.y, c2B.y);
                } else if (tj == 1) {
                    dsw2<32,     33>(va, c1A.x, c2A.x);
                    dsw2<160,   161>(va, c1A.y, c2A.y);
                    dsw2<32,     33>(vb, c1B.x, c2B.x);
                    dsw2<160,   161>(vb, c1B.y, c2B.y);
                } else if (tj == 2) {
                    dsw2<64,     65>(va, c1A.x, c2A.x);
                    dsw2<192,   193>(va, c1A.y, c2A.y);
                    dsw2<64,     65>(vb, c1B.x, c2B.x);
                    dsw2<192,   193>(vb, c1B.y, c2B.y);
                } else {
                    dsw2<96,     97>(va, c1A.x, c2A.x);
                    dsw2<224,   225>(va, c1A.y, c2A.y);
                    dsw2<96,     97>(vb, c1B.x, c2B.x);
                    dsw2<224,   225>(vb, c1B.y, c2B.y);
                }
            }
        }
    }
    __syncthreads();

    // ---- 2x2-block wavefront scan, 125 steps, 2 DPP/step ----
    const float one = 1.0f;
    float kA1 = 1.f;   // K[2d][2p+1] entering step
    float kB1 = 1.f;   // K[2d][2p+2] entering step
    float bM  = 1.f;   // a12 of previous step
    float rx  = 1.f;   // prev step's shr1(kB1) = K[2d][2p]

    const float2* cp = &coef[p];
    auto ldrow = [&](int q1) -> float2 {
        unsigned rc = (unsigned)q1 > 64u ? 64u : (unsigned)q1;
        return cp[rc * CO_STR];
    };

    float2 cb0 = ldrow(1 - p);
    float2 cb1 = ldrow(2 - p);
    float2 cb2 = ldrow(3 - p);
    float2 cb3 = ldrow(4 - p);
    float2 cb4 = ldrow(5 - p);

    auto step = [&](float2 cb) {
        const float nbB = dpp_shr1_old1(kB1, one);   // K[2d+2][2p]
        const float nbM = dpp_shr1_old1(bM,  one);   // K[2d+1][2p]
        const float c1 = cb.x, c2 = cb.y;
        const float a11 = __builtin_fmaf(c1, nbM + kA1, -(c2 * rx));
        const float a12 = __builtin_fmaf(c1, a11 + kB1, -(c2 * kA1));
        const float a21 = __builtin_fmaf(c1, nbB + a11, -(c2 * nbM));
        const float a22 = __builtin_fmaf(c1, a21 + a12, -(c2 * a11));
        rx = nbB; bM = a12; kA1 = a21; kB1 = a22;
    };

    // phase 1: T = 0..59 (fill present -> clamped prefetch)
#pragma unroll 5
    for (int T = 0; T < 60; ++T) {
        float2 cbn = ldrow(T + 6 - p);
        step(cb0);
        cb0 = cb1; cb1 = cb2; cb2 = cb3; cb3 = cb4; cb4 = cbn;
    }
    // phase 2: T = 60..119 (no fill; drain reads OOB-garbage-safe)
    int a2 = 33792 - 504 * p;   // byte addr of row (66-p), col p
#pragma unroll 5
    for (int T = 60; T < 120; ++T) {
        float2 cbn = *reinterpret_cast<const float2*>(lds + a2);
        a2 += 512;
        step(cb0);
        cb0 = cb1; cb1 = cb2; cb2 = cb3; cb3 = cb4; cb4 = cbn;
    }
    // epilogue: T = 120..124, no prefetch
    step(cb0); step(cb1); step(cb2); step(cb3); step(cb4);

    // K[126][126] = a22 of block (62,62), lane 62 at T=124
    if (p == 62) {
        out[a * 32 + b] = kB1;
    }
}

extern "C" void kernel_launch(void* const* d_in, const int* in_sizes, int n_in,
                              void* d_out, int out_size, void* d_ws, size_t ws_size,
                              hipStream_t stream)
{
    const float* xs = (const float*)d_in[0];
    const float* ys = (const float*)d_in[1];
    float* out = (float*)d_out;

    dim3 grid(32, 32, 1);   // x = b, y = a
    dim3 block(64, 1, 1);
    hipLaunchKernelGGL(sig_pde_kernel, grid, block, 0, stream, xs, ys, out);
}